// Round 6
// baseline (9114.133 us; speedup 1.0000x reference)
//
#include <hip/hip_runtime.h>
#include <stdint.h>

#define S_LEN 2048
#define NHEAD 16
#define DHEAD 64
#define DMODEL 1024
#define MROWS 8192  // B*S
#define QB 4        // q-rows per attention block

typedef unsigned short ushort_t;
typedef __attribute__((ext_vector_type(8))) __bf16 bf16x8;
typedef __attribute__((ext_vector_type(4))) float f32x4;

__device__ __forceinline__ float bf2f(ushort_t h) {
    union { unsigned int u; float f; } v; v.u = ((unsigned int)h) << 16; return v.f;
}
__device__ __forceinline__ ushort_t f2bf(float f) {
    union { float f; unsigned int u; } v; v.f = f;
    unsigned int u = v.u + 0x7fffu + ((v.u >> 16) & 1u);  // round-to-nearest-even
    return (ushort_t)(u >> 16);
}

// ---------------------------------------------------------------------------
// Dtype detection (verified in round 4: query is f32 -> flag=1). bf16 data
// read as uint32 has ~100% sane low half-words; f32 data ~25%.
// ---------------------------------------------------------------------------
__global__ void detect_dtype(const unsigned int* __restrict__ q, int* __restrict__ flag)
{
    __shared__ int cnt;
    if (threadIdx.x == 0) cnt = 0;
    __syncthreads();
    int c = 0;
    for (int i = 0; i < 8; ++i) {
        const unsigned int w = q[threadIdx.x * 8 + i];   // first 512 words
        const unsigned int lo = w & 0xffffu;
        const unsigned int e = (lo >> 7) & 0xffu;        // bf16 exponent field
        if (lo == 0u || (e >= 96u && e <= 160u)) ++c;    // "sane" bf16
    }
    atomicAdd(&cnt, c);
    __syncthreads();
    if (threadIdx.x == 0) flag[0] = (cnt < 400) ? 1 : 0;
}

// Stage 8 consecutive elements (16 B of bf16) into LDS, converting from f32
// if needed. idx is the ELEMENT index into src.
__device__ __forceinline__ void stage8(ushort_t* dst, const void* src, size_t idx, bool f32)
{
    if (f32) {
        const float* s = (const float*)src + idx;
        const float4 a = *(const float4*)s;
        const float4 b = *(const float4*)(s + 4);
        union { ushort_t u[8]; uint4 v; } p;
        p.u[0] = f2bf(a.x); p.u[1] = f2bf(a.y); p.u[2] = f2bf(a.z); p.u[3] = f2bf(a.w);
        p.u[4] = f2bf(b.x); p.u[5] = f2bf(b.y); p.u[6] = f2bf(b.z); p.u[7] = f2bf(b.w);
        *(uint4*)dst = p.v;
    } else {
        *(uint4*)dst = *(const uint4*)((const ushort_t*)src + idx);
    }
}

__device__ __forceinline__ float loadscal(const void* b, int i, bool f32)
{
    return f32 ? ((const float*)b)[i] : bf2f(((const ushort_t*)b)[i]);
}

// ---------------------------------------------------------------------------
// C = X @ W^T + bias, X:[M=8192,K=1024], W:[N=1024,K], out row-major [M,N].
// AF: runtime activation-dtype flag (dflag[0]) applies to X.
// BF: runtime weight-dtype flag (dflag[1]) applies to W and bias.
// OUTF: true -> out is float32, else bf16.
// 128x128 tile, BK=32, 256 threads = 4 waves in 2x2, each wave 64x64 of
// mfma_f32_16x16x32_bf16 (4x4 tiles).  (learn_hip m93-verified structure)
// ---------------------------------------------------------------------------
template <bool AF, bool BF, bool OUTF>
__global__ __launch_bounds__(256, 2)
void gemm_bt(const void* __restrict__ X, const void* __restrict__ W,
             const void* __restrict__ bias, void* __restrict__ out,
             const int* __restrict__ dflag)
{
    constexpr int K = DMODEL, N = DMODEL;
    __shared__ ushort_t As[128 * 32];
    __shared__ ushort_t Bs[128 * 32];
    const bool af32 = AF ? (dflag[0] != 0) : false;
    const bool bf32 = BF ? (dflag[1] != 0) : false;
    const int tid = threadIdx.x;
    const int lane = tid & 63;
    const int wave = tid >> 6;
    const int lrow = lane & 15, lq = lane >> 4;
    const int m0 = blockIdx.x * 128;
    const int n0 = blockIdx.y * 128;
    const int wr = (wave >> 1) * 64;
    const int wc = (wave & 1) * 64;

    const f32x4 zero4 = {0.f, 0.f, 0.f, 0.f};
    f32x4 acc[4][4];
#pragma unroll
    for (int i = 0; i < 4; ++i)
#pragma unroll
        for (int j = 0; j < 4; ++j) acc[i][j] = zero4;

    const int r0  = tid >> 2;          // staging row 0..63 (+64 on 2nd chunk)
    const int cc0 = (tid & 3) * 8;     // staging col {0,8,16,24}

    for (int k0 = 0; k0 < K; k0 += 32) {
#pragma unroll
        for (int i = 0; i < 2; ++i) {
            const int r = r0 + i * 64;
            stage8(&As[r * 32 + cc0], X, (size_t)(m0 + r) * K + k0 + cc0, af32);
            stage8(&Bs[r * 32 + cc0], W, (size_t)(n0 + r) * K + k0 + cc0, bf32);
        }
        __syncthreads();
        bf16x8 af[4], bfr[4];
#pragma unroll
        for (int t = 0; t < 4; ++t) {
            af[t]  = *(const bf16x8*)(&As[(wr + t * 16 + lrow) * 32 + lq * 8]);
            bfr[t] = *(const bf16x8*)(&Bs[(wc + t * 16 + lrow) * 32 + lq * 8]);
        }
#pragma unroll
        for (int mt = 0; mt < 4; ++mt)
#pragma unroll
            for (int nt = 0; nt < 4; ++nt)
                acc[mt][nt] = __builtin_amdgcn_mfma_f32_16x16x32_bf16(
                    af[mt], bfr[nt], acc[mt][nt], 0, 0, 0);
        __syncthreads();
    }

    // epilogue: C/D layout row=(lane>>4)*4+reg, col=lane&15
#pragma unroll
    for (int nt = 0; nt < 4; ++nt) {
        const int n = n0 + wc + nt * 16 + lrow;
        const float bv = loadscal(bias, n, bf32);
#pragma unroll
        for (int mt = 0; mt < 4; ++mt) {
            const int mbase = m0 + wr + mt * 16 + lq * 4;
#pragma unroll
            for (int r = 0; r < 4; ++r) {
                const float v = acc[mt][nt][r] + bv;
                const size_t o = (size_t)(mbase + r) * N + n;
                if (OUTF) ((float*)out)[o] = v;
                else      ((ushort_t*)out)[o] = f2bf(v);
            }
        }
    }
}

// ---------------------------------------------------------------------------
// Reference-literal attention (validated structure from round 5). Q,K,V,X all
// [B*S, 1024] row-major bf16, head h at columns h*64..h*64+63.
// Grid (S/QB, B*NHEAD), block 256. Per block: QB q-rows; all 2048 scores in
// LDS fp32; two-pass softmax; PV with fp32 accumulation.
// ---------------------------------------------------------------------------
__global__ __launch_bounds__(256, 2)
void attn_rows(const ushort_t* __restrict__ Q, const ushort_t* __restrict__ K,
               const ushort_t* __restrict__ V, const int* __restrict__ mask,
               ushort_t* __restrict__ X)
{
    __shared__ float sc[QB][S_LEN];      // 32 KB  scores -> probs
    __shared__ float qs[QB][64];         // 1 KB   pre-scaled q rows
    __shared__ float wred[QB][4];        // per-wave reduction scratch
    __shared__ float vred[4][QB][64];    // 4 KB   PV partials per key-group

    const int tid = threadIdx.x;
    const int wave = tid >> 6, lane = tid & 63;
    const int bh = blockIdx.y, b = bh >> 4, h = bh & 15;
    const int q0 = blockIdx.x * QB;
    const int coff = h * 64;
    const size_t rowb = (size_t)b * S_LEN;

    // ---- load Q rows, fold in 1/sqrt(DK) ----
    {
        const int qi = tid >> 6, d = tid & 63;   // 256 threads = QB*64
        qs[qi][d] = 0.125f * bf2f(Q[(rowb + q0 + qi) * DMODEL + coff + d]);
    }
    __syncthreads();

    // ---- pass 1: scores for all 2048 keys ----
    float lmax[QB];
#pragma unroll
    for (int qi = 0; qi < QB; ++qi) lmax[qi] = -1e30f;
    for (int rep = 0; rep < 8; ++rep) {
        const int k = rep * 256 + tid;
        const ushort_t* kr = &K[(rowb + k) * DMODEL + coff];
        float s[QB] = {0.f, 0.f, 0.f, 0.f};
#pragma unroll
        for (int d4 = 0; d4 < 16; ++d4) {
            const ushort4 kk = *(const ushort4*)(kr + d4 * 4);
            const float k0f = bf2f(kk.x), k1f = bf2f(kk.y);
            const float k2f = bf2f(kk.z), k3f = bf2f(kk.w);
#pragma unroll
            for (int qi = 0; qi < QB; ++qi)
                s[qi] += qs[qi][d4 * 4 + 0] * k0f + qs[qi][d4 * 4 + 1] * k1f
                       + qs[qi][d4 * 4 + 2] * k2f + qs[qi][d4 * 4 + 3] * k3f;
        }
#pragma unroll
        for (int qi = 0; qi < QB; ++qi) {
            if (mask[(size_t)(q0 + qi) * S_LEN + k] == 0) s[qi] = -1e9f;
            sc[qi][k] = s[qi];
            lmax[qi] = fmaxf(lmax[qi], s[qi]);
        }
    }
    // ---- block max ----
#pragma unroll
    for (int qi = 0; qi < QB; ++qi) {
        float v = lmax[qi];
#pragma unroll
        for (int off = 1; off < 64; off <<= 1) v = fmaxf(v, __shfl_xor(v, off, 64));
        if (lane == 0) wred[qi][wave] = v;
    }
    __syncthreads();
    float mrow[QB];
#pragma unroll
    for (int qi = 0; qi < QB; ++qi)
        mrow[qi] = fmaxf(fmaxf(wred[qi][0], wred[qi][1]),
                         fmaxf(wred[qi][2], wred[qi][3]));
    __syncthreads();   // all wred reads done before reuse below

    // ---- pass 2: exp + block sum ----
    float lsum[QB] = {0.f, 0.f, 0.f, 0.f};
    for (int rep = 0; rep < 8; ++rep) {
        const int k = rep * 256 + tid;
#pragma unroll
        for (int qi = 0; qi < QB; ++qi) {
            const float p = __expf(sc[qi][k] - mrow[qi]);
            sc[qi][k] = p;
            lsum[qi] += p;
        }
    }
#pragma unroll
    for (int qi = 0; qi < QB; ++qi) {
        float v = lsum[qi];
#pragma unroll
        for (int off = 1; off < 64; off <<= 1) v += __shfl_xor(v, off, 64);
        if (lane == 0) wred[qi][wave] = v;
    }
    __syncthreads();
    float lrow[QB];
#pragma unroll
    for (int qi = 0; qi < QB; ++qi)
        lrow[qi] = (wred[qi][0] + wred[qi][1]) + (wred[qi][2] + wred[qi][3]);

    // ---- pass 3: O = P V (key-groups of 512, coalesced over d) ----
    {
        const int kg = wave;            // 0..3
        const int d = lane;             // 0..63
        float acc[QB] = {0.f, 0.f, 0.f, 0.f};
        for (int k = kg * 512; k < kg * 512 + 512; ++k) {
            const float vv = bf2f(V[(rowb + k) * DMODEL + coff + d]);
#pragma unroll
            for (int qi = 0; qi < QB; ++qi) acc[qi] += sc[qi][k] * vv;
        }
#pragma unroll
        for (int qi = 0; qi < QB; ++qi) vred[kg][qi][d] = acc[qi];
    }
    __syncthreads();

    // ---- epilogue ----
    {
        const int qi = tid >> 6, d = tid & 63;
        const float o = ((vred[0][qi][d] + vred[1][qi][d]) +
                         (vred[2][qi][d] + vred[3][qi][d])) / lrow[qi];
        X[(rowb + q0 + qi) * DMODEL + coff + d] = f2bf(o);
    }
}

// ---------------------------------------------------------------------------
extern "C" void kernel_launch(void* const* d_in, const int* in_sizes, int n_in,
                              void* d_out, int out_size, void* d_ws, size_t ws_size,
                              hipStream_t stream)
{
    const void* query = d_in[0];
    const void* key   = d_in[1];
    const void* value = d_in[2];
    const int*  mask  = (const int*)d_in[3];
    const void* w_q = d_in[4];
    const void* b_q = d_in[5];
    const void* w_k = d_in[6];
    const void* b_k = d_in[7];
    const void* w_v = d_in[8];
    const void* b_v = d_in[9];
    const void* w_o = d_in[10];
    const void* b_o = d_in[11];

    // Workspace: [Kp 16MiB][Vp 16MiB][Xp 16MiB][dflag 8B]  (round 5 validated
    // ws_size >= 48 MiB).  Q (bf16, 16 MiB) lives inside d_out (f32, 32 MiB):
    // consumed by attn_rows before the final GEMM overwrites d_out.
    const size_t TEN = (size_t)MROWS * DMODEL;   // 8M elements
    ushort_t* Kp = (ushort_t*)d_ws;
    ushort_t* Vp = Kp + TEN;
    ushort_t* Xp = Vp + TEN;
    int* dflag   = (int*)(Xp + TEN);             // [0]=activations f32, [1]=weights f32
    ushort_t* Qp = (ushort_t*)d_out;

    detect_dtype<<<1, 64, 0, stream>>>((const unsigned int*)query, dflag + 0);
    detect_dtype<<<1, 64, 0, stream>>>((const unsigned int*)w_q,   dflag + 1);

    const dim3 gg(64, 8);
    gemm_bt<true, true, false><<<gg, 256, 0, stream>>>(query, w_q, b_q, Qp, dflag);
    gemm_bt<true, true, false><<<gg, 256, 0, stream>>>(key,   w_k, b_k, Kp, dflag);
    gemm_bt<true, true, false><<<gg, 256, 0, stream>>>(value, w_v, b_v, Vp, dflag);

    attn_rows<<<dim3(S_LEN / QB, 64), 256, 0, stream>>>(Qp, Kp, Vp, mask, Xp);

    gemm_bt<false, true, true><<<gg, 256, 0, stream>>>(Xp, w_o, b_o, d_out, dflag);
}

// Round 7
// 697.743 us; speedup vs baseline: 13.0623x; 13.0623x over previous
//
#include <hip/hip_runtime.h>
#include <stdint.h>

#define S_LEN 2048
#define NHEAD 16
#define DHEAD 64
#define DMODEL 1024
#define MROWS 8192  // B*S

typedef unsigned short ushort_t;
typedef __attribute__((ext_vector_type(8))) __bf16 bf16x8;
typedef __attribute__((ext_vector_type(4))) float f32x4;

__device__ __forceinline__ float bf2f(ushort_t h) {
    union { unsigned int u; float f; } v; v.u = ((unsigned int)h) << 16; return v.f;
}
__device__ __forceinline__ ushort_t f2bf(float f) {
    union { float f; unsigned int u; } v; v.f = f;
    unsigned int u = v.u + 0x7fffu + ((v.u >> 16) & 1u);  // round-to-nearest-even
    return (ushort_t)(u >> 16);
}

// ---------------------------------------------------------------------------
// Dtype detection (HW-verified round 4/6: query f32 -> flag=1).
// ---------------------------------------------------------------------------
__global__ void detect_dtype(const unsigned int* __restrict__ q, int* __restrict__ flag)
{
    __shared__ int cnt;
    if (threadIdx.x == 0) cnt = 0;
    __syncthreads();
    int c = 0;
    for (int i = 0; i < 8; ++i) {
        const unsigned int w = q[threadIdx.x * 8 + i];   // first 512 words
        const unsigned int lo = w & 0xffffu;
        const unsigned int e = (lo >> 7) & 0xffu;        // bf16 exponent field
        if (lo == 0u || (e >= 96u && e <= 160u)) ++c;    // "sane" bf16
    }
    atomicAdd(&cnt, c);
    __syncthreads();
    if (threadIdx.x == 0) flag[0] = (cnt < 400) ? 1 : 0;
}

// ---------------------------------------------------------------------------
// mask -> per 128x128 tile flag (1 = all nonzero -> skip elementwise path)
// ---------------------------------------------------------------------------
__global__ void mask_flags(const int* __restrict__ mask, int* __restrict__ flags)
{
    __shared__ int ok_s;
    if (threadIdx.x == 0) ok_s = 1;
    __syncthreads();
    const int t = blockIdx.x;            // 0..255
    const int tq = t >> 4, tk = t & 15;
    int ok = 1;
    for (int i = 0; i < 64; ++i) {
        const int idx = i * 256 + threadIdx.x;    // 0..16383
        const int r = idx >> 7, c = idx & 127;
        if (mask[(size_t)(tq * 128 + r) * S_LEN + tk * 128 + c] == 0) { ok = 0; break; }
    }
    if (!ok) atomicAnd(&ok_s, 0);
    __syncthreads();
    if (threadIdx.x == 0) flags[t] = ok_s;
}

// Stage 8 consecutive elements (16 B of bf16) into LDS, converting from f32
// if needed. idx is the ELEMENT index into src.
__device__ __forceinline__ void stage8(ushort_t* dst, const void* src, size_t idx, bool f32)
{
    if (f32) {
        const float* s = (const float*)src + idx;
        const float4 a = *(const float4*)s;
        const float4 b = *(const float4*)(s + 4);
        union { ushort_t u[8]; uint4 v; } p;
        p.u[0] = f2bf(a.x); p.u[1] = f2bf(a.y); p.u[2] = f2bf(a.z); p.u[3] = f2bf(a.w);
        p.u[4] = f2bf(b.x); p.u[5] = f2bf(b.y); p.u[6] = f2bf(b.z); p.u[7] = f2bf(b.w);
        *(uint4*)dst = p.v;
    } else {
        *(uint4*)dst = *(const uint4*)((const ushort_t*)src + idx);
    }
}

__device__ __forceinline__ float loadscal(const void* b, int i, bool f32)
{
    return f32 ? ((const float*)b)[i] : bf2f(((const ushort_t*)b)[i]);
}

// ---------------------------------------------------------------------------
// C = X @ W^T + bias, X:[M=8192,K=1024], W:[N=1024,K], out row-major [M,N].
// AF: runtime activation-dtype flag (dflag[0]) applies to X.
// BF: runtime weight-dtype flag (dflag[1]) applies to W and bias.
// OUTF: true -> out is float32, else bf16.
// (PASS-verified in round 6, unchanged.)
// ---------------------------------------------------------------------------
template <bool AF, bool BF, bool OUTF>
__global__ __launch_bounds__(256, 2)
void gemm_bt(const void* __restrict__ X, const void* __restrict__ W,
             const void* __restrict__ bias, void* __restrict__ out,
             const int* __restrict__ dflag)
{
    constexpr int K = DMODEL, N = DMODEL;
    __shared__ ushort_t As[128 * 32];
    __shared__ ushort_t Bs[128 * 32];
    const bool af32 = AF ? (dflag[0] != 0) : false;
    const bool bf32 = BF ? (dflag[1] != 0) : false;
    const int tid = threadIdx.x;
    const int lane = tid & 63;
    const int wave = tid >> 6;
    const int lrow = lane & 15, lq = lane >> 4;
    const int m0 = blockIdx.x * 128;
    const int n0 = blockIdx.y * 128;
    const int wr = (wave >> 1) * 64;
    const int wc = (wave & 1) * 64;

    const f32x4 zero4 = {0.f, 0.f, 0.f, 0.f};
    f32x4 acc[4][4];
#pragma unroll
    for (int i = 0; i < 4; ++i)
#pragma unroll
        for (int j = 0; j < 4; ++j) acc[i][j] = zero4;

    const int r0  = tid >> 2;
    const int cc0 = (tid & 3) * 8;

    for (int k0 = 0; k0 < K; k0 += 32) {
#pragma unroll
        for (int i = 0; i < 2; ++i) {
            const int r = r0 + i * 64;
            stage8(&As[r * 32 + cc0], X, (size_t)(m0 + r) * K + k0 + cc0, af32);
            stage8(&Bs[r * 32 + cc0], W, (size_t)(n0 + r) * K + k0 + cc0, bf32);
        }
        __syncthreads();
        bf16x8 af[4], bfr[4];
#pragma unroll
        for (int t = 0; t < 4; ++t) {
            af[t]  = *(const bf16x8*)(&As[(wr + t * 16 + lrow) * 32 + lq * 8]);
            bfr[t] = *(const bf16x8*)(&Bs[(wc + t * 16 + lrow) * 32 + lq * 8]);
        }
#pragma unroll
        for (int mt = 0; mt < 4; ++mt)
#pragma unroll
            for (int nt = 0; nt < 4; ++nt)
                acc[mt][nt] = __builtin_amdgcn_mfma_f32_16x16x32_bf16(
                    af[mt], bfr[nt], acc[mt][nt], 0, 0, 0);
        __syncthreads();
    }

#pragma unroll
    for (int nt = 0; nt < 4; ++nt) {
        const int n = n0 + wc + nt * 16 + lrow;
        const float bv = loadscal(bias, n, bf32);
#pragma unroll
        for (int mt = 0; mt < 4; ++mt) {
            const int mbase = m0 + wr + mt * 16 + lq * 4;
#pragma unroll
            for (int r = 0; r < 4; ++r) {
                const float v = acc[mt][nt][r] + bv;
                const size_t o = (size_t)(mbase + r) * N + n;
                if (OUTF) ((float*)out)[o] = v;
                else      ((ushort_t*)out)[o] = f2bf(v);
            }
        }
    }
}

// ---------------------------------------------------------------------------
// MFMA flash attention. Q,K,V,X in [B*S, 1024] row-major bf16 (round-6
// verified layout); head h = columns h*64..h*64+63. Grid (16 q-tiles, 64 bh),
// block 256 = 4 waves; wave w owns q rows [q0+32w, +32) as 2 m-tiles.
// Per 128-key tile: K staged [key][d] (stride 72), V staged TRANSPOSED
// [d][key] (stride 130, bank-audited), QK^T + online softmax (C-layout rows
// = 16 consecutive lanes), P relayout C->A via per-wave LDS, PV MFMA.
// ---------------------------------------------------------------------------
__global__ __launch_bounds__(256, 2)
void attn_mfma(const ushort_t* __restrict__ Q, const ushort_t* __restrict__ K,
               const ushort_t* __restrict__ V, const int* __restrict__ mask,
               const int* __restrict__ flags, ushort_t* __restrict__ X)
{
    constexpr int KP = 72;    // K tile row stride
    constexpr int VP = 130;   // V^T tile row stride (even; bank-spread)
    constexpr int PP = 72;    // P tile row stride
    __shared__ ushort_t Ks[128 * KP];       // 18.0 KB
    __shared__ ushort_t VTs[64 * VP];       // 16.3 KB
    __shared__ ushort_t Ps[4][32 * PP];     // 18.0 KB (per-wave)

    const int tid = threadIdx.x;
    const int lane = tid & 63;
    const int wave = tid >> 6;
    const int lrow = lane & 15, lq = lane >> 4;
    const int bh = blockIdx.y, b = bh >> 4, h = bh & 15;
    const int q0 = blockIdx.x * 128;
    const int qw = q0 + wave * 32;
    const int coff = h * 64;
    const size_t rowb = (size_t)b * S_LEN;

    // Q fragments (A-operand: m=lrow, k-chunk=lq*8) live in registers
    bf16x8 qf[2][2];
#pragma unroll
    for (int mt = 0; mt < 2; ++mt)
#pragma unroll
        for (int ks = 0; ks < 2; ++ks)
            qf[mt][ks] = *(const bf16x8*)(
                &Q[(rowb + qw + mt * 16 + lrow) * DMODEL + coff + ks * 32 + lq * 8]);

    const f32x4 zero4 = {0.f, 0.f, 0.f, 0.f};
    f32x4 o[2][4];
    float mr[2][4], lr[2][4];
#pragma unroll
    for (int mt = 0; mt < 2; ++mt) {
#pragma unroll
        for (int nt = 0; nt < 4; ++nt) o[mt][nt] = zero4;
#pragma unroll
        for (int r = 0; r < 4; ++r) { mr[mt][r] = -1e30f; lr[mt][r] = 0.f; }
    }

    ushort_t* const pw = &Ps[wave][0];

    for (int kt = 0; kt < 16; ++kt) {
        const int k0 = kt * 128;
        // ---- stage K tile [128 keys][64 d] ----
#pragma unroll
        for (int i = 0; i < 4; ++i) {
            const int c = tid + i * 256;            // 1024 8-elem chunks
            const int r = c >> 3, cc = (c & 7) * 8;
            *(uint4*)(&Ks[r * KP + cc]) =
                *(const uint4*)(&K[(rowb + k0 + r) * DMODEL + coff + cc]);
        }
        // ---- stage V tile transposed: VTs[d][key], pair-of-rows scheme ----
#pragma unroll
        for (int i = 0; i < 2; ++i) {
            const int c = tid + i * 256;            // 512 chunks
            const int k2 = c >> 3;                  // key pair 0..63
            const int cc = (c & 7) * 8;             // d chunk
            union { uint4 v; ushort_t u[8]; } a, bb;
            a.v  = *(const uint4*)(&V[(rowb + k0 + 2 * k2)     * DMODEL + coff + cc]);
            bb.v = *(const uint4*)(&V[(rowb + k0 + 2 * k2 + 1) * DMODEL + coff + cc]);
#pragma unroll
            for (int j = 0; j < 8; ++j) {
                const unsigned int pk = (unsigned int)a.u[j] | ((unsigned int)bb.u[j] << 16);
                *(unsigned int*)(&VTs[(cc + j) * VP + 2 * k2]) = pk;
            }
        }
        __syncthreads();

        // ---- S = Q K^T (C-layout: q=lq*4+r, key=lrow) ----
        f32x4 s[2][8];
#pragma unroll
        for (int mt = 0; mt < 2; ++mt)
#pragma unroll
            for (int nt = 0; nt < 8; ++nt) s[mt][nt] = zero4;
#pragma unroll
        for (int nt = 0; nt < 8; ++nt) {
#pragma unroll
            for (int ks = 0; ks < 2; ++ks) {
                const bf16x8 kf = *(const bf16x8*)(&Ks[(nt * 16 + lrow) * KP + ks * 32 + lq * 8]);
                s[0][nt] = __builtin_amdgcn_mfma_f32_16x16x32_bf16(qf[0][ks], kf, s[0][nt], 0, 0, 0);
                s[1][nt] = __builtin_amdgcn_mfma_f32_16x16x32_bf16(qf[1][ks], kf, s[1][nt], 0, 0, 0);
            }
        }

        // ---- scale + mask ----
#pragma unroll
        for (int mt = 0; mt < 2; ++mt)
#pragma unroll
            for (int nt = 0; nt < 8; ++nt)
#pragma unroll
                for (int r = 0; r < 4; ++r) s[mt][nt][r] *= 0.125f;  // 1/sqrt(64)
        if (!flags[blockIdx.x * 16 + kt]) {
            for (int mt = 0; mt < 2; ++mt)
                for (int nt = 0; nt < 8; ++nt)
                    for (int r = 0; r < 4; ++r) {
                        const int qi = qw + mt * 16 + lq * 4 + r;
                        const int ki = k0 + nt * 16 + lrow;
                        if (mask[(size_t)qi * S_LEN + ki] == 0) s[mt][nt][r] = -1e9f;
                    }
        }

        // ---- online softmax (row = 16 consecutive lanes, fixed lq) ----
#pragma unroll
        for (int mt = 0; mt < 2; ++mt) {
#pragma unroll
            for (int r = 0; r < 4; ++r) {
                float v = s[mt][0][r];
#pragma unroll
                for (int nt = 1; nt < 8; ++nt) v = fmaxf(v, s[mt][nt][r]);
#pragma unroll
                for (int off = 1; off < 16; off <<= 1) v = fmaxf(v, __shfl_xor(v, off, 64));
                const float mn = fmaxf(mr[mt][r], v);
                const float alpha = __expf(mr[mt][r] - mn);
                mr[mt][r] = mn;
                float rs = 0.f;
#pragma unroll
                for (int nt = 0; nt < 8; ++nt) {
                    const float p = __expf(s[mt][nt][r] - mn);
                    s[mt][nt][r] = p;
                    rs += p;
                }
#pragma unroll
                for (int off = 1; off < 16; off <<= 1) rs += __shfl_xor(rs, off, 64);
                lr[mt][r] = lr[mt][r] * alpha + rs;
#pragma unroll
                for (int nt = 0; nt < 4; ++nt) o[mt][nt][r] *= alpha;
            }
        }

        // ---- O += P V in two 64-key halves via per-wave LDS relayout ----
#pragma unroll
        for (int half = 0; half < 2; ++half) {
            // write P (C-layout) into pw[q][k_local]
#pragma unroll
            for (int mt = 0; mt < 2; ++mt)
#pragma unroll
                for (int nt = 0; nt < 4; ++nt)
#pragma unroll
                    for (int r = 0; r < 4; ++r)
                        pw[(mt * 16 + lq * 4 + r) * PP + nt * 16 + lrow] =
                            f2bf(s[mt][half * 4 + nt][r]);
            // read A-layout fragments and multiply against V^T
#pragma unroll
            for (int ks = 0; ks < 2; ++ks) {
                const bf16x8 pf0 = *(const bf16x8*)(&pw[lrow * PP + ks * 32 + lq * 8]);
                const bf16x8 pf1 = *(const bf16x8*)(&pw[(16 + lrow) * PP + ks * 32 + lq * 8]);
                const int kb = half * 64 + ks * 32;       // key offset in tile
#pragma unroll
                for (int nt = 0; nt < 4; ++nt) {
                    const bf16x8 vf = *(const bf16x8*)(
                        &VTs[(nt * 16 + lrow) * VP + kb + lq * 8]);
                    o[0][nt] = __builtin_amdgcn_mfma_f32_16x16x32_bf16(pf0, vf, o[0][nt], 0, 0, 0);
                    o[1][nt] = __builtin_amdgcn_mfma_f32_16x16x32_bf16(pf1, vf, o[1][nt], 0, 0, 0);
                }
            }
        }
        __syncthreads();
    }

    // ---- epilogue: X row-major, head columns ----
#pragma unroll
    for (int mt = 0; mt < 2; ++mt) {
#pragma unroll
        for (int r = 0; r < 4; ++r) {
            const float inv = 1.f / lr[mt][r];
            const int si = qw + mt * 16 + lq * 4 + r;
#pragma unroll
            for (int nt = 0; nt < 4; ++nt) {
                const int dk = nt * 16 + lrow;
                X[(rowb + si) * DMODEL + coff + dk] = f2bf(o[mt][nt][r] * inv);
            }
        }
    }
}

// ---------------------------------------------------------------------------
extern "C" void kernel_launch(void* const* d_in, const int* in_sizes, int n_in,
                              void* d_out, int out_size, void* d_ws, size_t ws_size,
                              hipStream_t stream)
{
    const void* query = d_in[0];
    const void* key   = d_in[1];
    const void* value = d_in[2];
    const int*  mask  = (const int*)d_in[3];
    const void* w_q = d_in[4];
    const void* b_q = d_in[5];
    const void* w_k = d_in[6];
    const void* b_k = d_in[7];
    const void* w_v = d_in[8];
    const void* b_v = d_in[9];
    const void* w_o = d_in[10];
    const void* b_o = d_in[11];

    // Workspace: [Kp 16MiB][Vp 16MiB][Xp 16MiB][dflag 8B][flags 1KB]
    // (>=48MiB verified round 6). Q (bf16) lives in d_out (f32, 32 MiB):
    // consumed by attn_mfma before the final GEMM overwrites d_out.
    const size_t TEN = (size_t)MROWS * DMODEL;   // 8M elements
    ushort_t* Kp = (ushort_t*)d_ws;
    ushort_t* Vp = Kp + TEN;
    ushort_t* Xp = Vp + TEN;
    int* dflag   = (int*)(Xp + TEN);             // [0]=act f32, [1]=weights f32
    int* flags   = dflag + 2;                    // 256 tile flags
    ushort_t* Qp = (ushort_t*)d_out;

    detect_dtype<<<1, 64, 0, stream>>>((const unsigned int*)query, dflag + 0);
    detect_dtype<<<1, 64, 0, stream>>>((const unsigned int*)w_q,   dflag + 1);
    mask_flags<<<256, 256, 0, stream>>>(mask, flags);

    const dim3 gg(64, 8);
    gemm_bt<true, true, false><<<gg, 256, 0, stream>>>(query, w_q, b_q, Qp, dflag);
    gemm_bt<true, true, false><<<gg, 256, 0, stream>>>(key,   w_k, b_k, Kp, dflag);
    gemm_bt<true, true, false><<<gg, 256, 0, stream>>>(value, w_v, b_v, Vp, dflag);

    attn_mfma<<<dim3(16, 64), 256, 0, stream>>>(Qp, Kp, Vp, mask, flags, Xp);

    gemm_bt<false, true, true><<<gg, 256, 0, stream>>>(Xp, w_o, b_o, d_out, dflag);
}